// Round 10
// baseline (155.132 us; speedup 1.0000x reference)
//
#include <hip/hip_runtime.h>

#define MDIM 512
#define LCH  31
#define CDIM 542   // MD + L - 1
#define INW  1024
#define RS   (INW*LCH)          // floats per input row = 31744
#define NELEM (MDIM*MDIM*LCH)   // 8126464
#define GB3  2048               // k3/k4 grid blocks

#define TNK  32                 // output n-cols per k1 tile
#define NT   16                 // tiles per row (512/32)
#define MGRP 4                  // output rows per k1 block
#define NQ   128                // m-quads (512/4)

// ws layout (floats): part[quad][tile][mm][128], yn, pmaxY, pmaxT, scl, cnt
#define PART_OFF 0
#define PART_SZ  (NQ*NT*MGRP*128)        // 1048576
#define YN_OFF   (PART_OFF + PART_SZ)
#define PMY_OFF  (YN_OFF + MDIM*CDIM)
#define PMT_OFF  (PMY_OFF + MDIM)
#define SCL_OFF  (PMT_OFF + GB3)
#define CNT_OFF  (SCL_OFF + 2)           // 2 ints (as float slots)

// K1: fused bilinear-resize + l-conv + H-mult + CASSI diagonal partial sums.
// Block = (m-quad g, n-tile of 32). 10 input rows serve FOUR output rows
// (X touched 1.25x). Vertical combine in registers while streaming rows
// (row base pointers are block-uniform -> SGPR). No Xm intermediate: the
// xm tile is reduced along diagonals (c = n + l) into ws partials.
// Clamped/garbage values are only ever consumed with zero weights:
//   col -1 / 1024 -> wx0/wx3 = 0 at n = 0/511
//   row -1 / 1024 -> W[0][0]/W[3][3] = 0 at m = 0/511
__global__ __launch_bounds__(256) void k1_fused(const float* __restrict__ X,
                                                const float* __restrict__ H,
                                                float* __restrict__ part,
                                                int* __restrict__ cnt) {
    __shared__ float xv[MGRP][2048];     // vertically-resized tiles (32 KB)
    __shared__ float xm[MGRP][32][33];   // H*conv tiles, padded (16.9 KB)

    const int bid = blockIdx.x;
    const int t   = bid & (NT-1);
    const int g   = bid >> 4;
    const int n0  = t * TNK;
    const int tid = threadIdx.x;
    const int qa  = 1984*t - 32;         // float4-aligned staged-q origin

    if (bid == 0 && tid < 2) cnt[tid] = 0;   // arm last-block counters

    // vertical weights for the 4 outputs; W[k][a], taps rr = 2k+a
    float W[4][4];
    #pragma unroll
    for (int k = 0; k < 4; ++k) {
        W[k][0]=0.125f; W[k][1]=0.375f; W[k][2]=0.375f; W[k][3]=0.125f;
    }
    if (g == 0)      { const float s=1.0f/0.875f; W[0][0]=0.f; W[0][1]=0.375f*s; W[0][2]=0.375f*s; W[0][3]=0.125f*s; }
    if (g == NQ-1)   { const float s=1.0f/0.875f; W[3][3]=0.f; W[3][0]=0.125f*s; W[3][1]=0.375f*s; W[3][2]=0.375f*s; }

    const float* rowp[10];
    #pragma unroll
    for (int rr = 0; rr < 10; ++rr)
        rowp[rr] = X + (size_t)min(max(8*g - 1 + rr, 0), INW-1) * RS;

    // ---- phase 1: stream 10 rows, vertical 4-tap for 4 outputs ----
    #pragma unroll
    for (int j = 0; j < 2; ++j) {
        const int u = tid + 256*j;
        const int q = min(max(qa + 4*u, 0), RS - 4);  // clamp -> zero-weight taps
        float4 acc[4];
        #pragma unroll
        for (int k = 0; k < 4; ++k) acc[k] = make_float4(0.f,0.f,0.f,0.f);
        #pragma unroll
        for (int rr = 0; rr < 10; ++rr) {
            const float4 r = *(const float4*)(rowp[rr] + q);
            #pragma unroll
            for (int k = 0; k < 4; ++k) {
                if (rr >= 2*k && rr <= 2*k + 3) {       // compile-time predicate
                    const float w = W[k][rr - 2*k];
                    acc[k].x = fmaf(w, r.x, acc[k].x);
                    acc[k].y = fmaf(w, r.y, acc[k].y);
                    acc[k].z = fmaf(w, r.z, acc[k].z);
                    acc[k].w = fmaf(w, r.w, acc[k].w);
                }
            }
        }
        #pragma unroll
        for (int k = 0; k < 4; ++k) *(float4*)&xv[k][4*u] = acc[k];
    }
    __syncthreads();

    // ---- phase 2: l-conv + horizontal 4-tap + H multiply -> xm tiles ----
    // xv[mm][i] holds vert(q = qa + i); tap (col = 2n-1+b, l) at
    // i = 2*nl*31 + 31*b + l + 1  (max 2046 < 2048).
    const size_t hbase = ((size_t)(MGRP*g)*MDIM + n0)*LCH;
    for (int idx = tid; idx < MGRP*TNK*LCH; idx += 256) {   // 3968
        const int mm = idx / (TNK*LCH);
        const int r2 = idx - mm*(TNK*LCH);
        const int nl = r2 / 31;
        const int l  = r2 - nl*31;
        const int n  = n0 + nl;
        float wx0=0.125f, wx1=0.375f, wx2=0.375f, wx3=0.125f;
        if (n == 0)      wx0 = 0.f;
        if (n == MDIM-1) wx3 = 0.f;
        if (n == 0 || n == MDIM-1) {
            const float s = 1.0f/0.875f;
            wx0*=s; wx1*=s; wx2*=s; wx3*=s;
        }
        const float wb4[4] = {wx0, wx1, wx2, wx3};
        const float* xvm = xv[mm];
        const int ib = 2*nl*31 + l + 1;
        float acc = 0.f;
        #pragma unroll
        for (int b = 0; b < 4; ++b) {
            const float* q = xvm + ib + 31*b;
            float c = 0.5f*q[0];
            if (l > 0)  c += 0.25f*q[-1];
            if (l < 30) c += 0.25f*q[1];
            acc = fmaf(wb4[b], c, acc);
        }
        xm[mm][nl][l] = acc * H[hbase + (size_t)mm*(MDIM*LCH) + r2];
    }
    __syncthreads();

    // ---- phase 3: diagonal partial sums: cl = c - n0 in [0,62), split halves
    for (int base = 0; base < 496; base += 256) {
        const int idx = base + tid;
        if (idx < 496) {
            const int mm = idx / 124;
            const int r3 = idx - mm*124;
            const int h  = r3 >= 62;
            const int cl = h ? r3 - 62 : r3;
            const int ilo = max(0, cl - (TNK-1));
            const int ihi = min(30, cl);
            const int mid = (ilo + ihi + 1) >> 1;
            const int lo  = h ? mid : ilo;
            const int hi  = h ? ihi : mid - 1;
            float s = 0.f;
            for (int i = lo; i <= hi; ++i)
                s += xm[mm][cl - i][i];          // stride-33 -> conflict-free
            part[(((size_t)g*NT + t)*MGRP + mm)*128 + h*64 + cl] = s;
        }
    }
}

// K2_lite: yn[m][c] from tile partials; per-row max; LAST block reduces
// pmaxY -> scl[0] = 1/maxY (deterministic: single reducer, max order-free).
__global__ __launch_bounds__(256) void k2_lite(const float* __restrict__ part,
                                               float* __restrict__ yn,
                                               float* __restrict__ pmaxY,
                                               float* __restrict__ scl,
                                               int* __restrict__ cnt) {
    const int m = blockIdx.x;
    const int g = m >> 2, mm = m & 3;
    float lmax = -3.4e38f;
    for (int c = threadIdx.x; c < CDIM; c += 256) {
        float s = 0.f;
        const int tlo = max(0, (c - 30) >> 5);
        const int thi = min(NT - 1, c >> 5);
        for (int t = tlo; t <= thi; ++t) {
            const int cl = c - TNK*t;               // in [0,62)
            const float* pp = part + (((size_t)g*NT + t)*MGRP + mm)*128;
            s += pp[cl] + pp[64 + cl];
        }
        yn[m*CDIM + c] = s;
        lmax = fmaxf(lmax, s);
    }
    __shared__ float red[256];
    __shared__ int isLast;
    red[threadIdx.x] = lmax; __syncthreads();
    for (int s = 128; s > 0; s >>= 1) {
        if ((int)threadIdx.x < s)
            red[threadIdx.x] = fmaxf(red[threadIdx.x], red[threadIdx.x+s]);
        __syncthreads();
    }
    if (threadIdx.x == 0) {
        pmaxY[m] = red[0];
        __threadfence();
        isLast = (atomicAdd(cnt + 0, 1) == (int)gridDim.x - 1);
    }
    __syncthreads();
    if (isLast) {
        __threadfence();
        float lm = -3.4e38f;
        for (int i = threadIdx.x; i < MDIM; i += 256)
            lm = fmaxf(lm, pmaxY[i]);
        red[threadIdx.x] = lm; __syncthreads();
        for (int s = 128; s > 0; s >>= 1) {
            if ((int)threadIdx.x < s)
                red[threadIdx.x] = fmaxf(red[threadIdx.x], red[threadIdx.x+s]);
            __syncthreads();
        }
        if (threadIdx.x == 0) { scl[0] = 1.0f / red[0]; cnt[0] = 0; }
    }
}

// t(idx) = H[idx] * conv_i(yn/My - y at c=n+i)  -- shared by k3 (max) and k4
__device__ __forceinline__ float t_elem(int idx,
                                        const float* __restrict__ yn,
                                        const float* __restrict__ y,
                                        const float* __restrict__ H,
                                        float inv) {
    const int i    = idx % LCH;
    const int rest = idx / LCH;
    const int n    = rest & (MDIM-1);
    const int m    = rest >> 9;
    const int c    = n + i;
    const float* ynr = yn + (size_t)m*CDIM;
    const float* yr  = y  + (size_t)m*CDIM;
    float v = 0.5f * (ynr[c]*inv - yr[c]);
    if (i > 0)     v += 0.25f*(ynr[c-1]*inv - yr[c-1]);
    if (i < LCH-1) v += 0.25f*(ynr[c+1]*inv - yr[c+1]);
    return H[idx]*v;
}

// K3: block-max of t -> pmaxT[bid]; LAST block reduces -> scl[1] = 1/maxT.
__global__ __launch_bounds__(256) void k3_max(const float* __restrict__ yn,
                                              const float* __restrict__ y,
                                              const float* __restrict__ H,
                                              float* __restrict__ scl,
                                              float* __restrict__ pmaxT,
                                              int* __restrict__ cnt) {
    const float inv = scl[0];
    float lmax = -3.4e38f;
    for (int idx = blockIdx.x*blockDim.x + threadIdx.x; idx < NELEM;
         idx += GB3*256)
        lmax = fmaxf(lmax, t_elem(idx, yn, y, H, inv));
    __shared__ float red[256];
    __shared__ int isLast;
    red[threadIdx.x] = lmax; __syncthreads();
    for (int s = 128; s > 0; s >>= 1) {
        if ((int)threadIdx.x < s)
            red[threadIdx.x] = fmaxf(red[threadIdx.x], red[threadIdx.x+s]);
        __syncthreads();
    }
    if (threadIdx.x == 0) {
        pmaxT[blockIdx.x] = red[0];
        __threadfence();
        isLast = (atomicAdd(cnt + 1, 1) == (int)gridDim.x - 1);
    }
    __syncthreads();
    if (isLast) {
        __threadfence();
        float lm = -3.4e38f;
        for (int i = threadIdx.x; i < GB3; i += 256)
            lm = fmaxf(lm, pmaxT[i]);
        red[threadIdx.x] = lm; __syncthreads();
        for (int s = 128; s > 0; s >>= 1) {
            if ((int)threadIdx.x < s)
                red[threadIdx.x] = fmaxf(red[threadIdx.x], red[threadIdx.x+s]);
            __syncthreads();
        }
        if (threadIdx.x == 0) { scl[1] = 1.0f / red[0]; cnt[1] = 0; }
    }
}

// K4: recompute t, scale by 1/maxT, write out (coalesced, single pass).
__global__ __launch_bounds__(256) void k4_out(const float* __restrict__ yn,
                                              const float* __restrict__ y,
                                              const float* __restrict__ H,
                                              const float* __restrict__ scl,
                                              float* __restrict__ out) {
    const float inv  = scl[0];
    const float invT = scl[1];
    for (int idx = blockIdx.x*blockDim.x + threadIdx.x; idx < NELEM;
         idx += GB3*256)
        out[idx] = t_elem(idx, yn, y, H, inv) * invT;
}

extern "C" void kernel_launch(void* const* d_in, const int* in_sizes, int n_in,
                              void* d_out, int out_size, void* d_ws, size_t ws_size,
                              hipStream_t stream) {
    const float* X = (const float*)d_in[0];
    const float* y = (const float*)d_in[1];
    const float* H = (const float*)d_in[2];
    float* out = (float*)d_out;
    float* ws  = (float*)d_ws;

    float* part  = ws + PART_OFF;
    float* yn    = ws + YN_OFF;
    float* pmaxY = ws + PMY_OFF;
    float* pmaxT = ws + PMT_OFF;
    float* scl   = ws + SCL_OFF;           // [0]=1/maxY, [1]=1/maxT
    int*   cnt   = (int*)(ws + CNT_OFF);   // last-block counters

    k1_fused<<<NQ*NT, 256, 0, stream>>>(X, H, part, cnt);       // 2048 blocks
    k2_lite<<<MDIM, 256, 0, stream>>>(part, yn, pmaxY, scl, cnt);
    k3_max<<<GB3, 256, 0, stream>>>(yn, y, H, scl, pmaxT, cnt);
    k4_out<<<GB3, 256, 0, stream>>>(yn, y, H, scl, out);
}

// Round 12
// 94.041 us; speedup vs baseline: 1.6496x; 1.6496x over previous
//
#include <hip/hip_runtime.h>

#define MDIM 512
#define LCH  31
#define CDIM 542   // MD + L - 1
#define INW  1024
#define RS   (INW*LCH)          // floats per input row = 31744
#define NELEM (MDIM*MDIM*LCH)   // 8126464
#define GB3  2048               // k3/k4 grid blocks

#define TNK  16                 // output n-cols per k1 tile
#define NT2  32                 // tiles per row (512/16)
#define MGRP 4                  // output rows per k1 block
#define NG   128                // m-groups (512/4)
#define SEGF 1056               // staged floats per row-tile (34 cols x 31, padded)
#define DIAG 46                 // distinct c per tile: TNK + LCH - 1

// ws layout (floats): part[g][t][mm][128], yn, pmaxY[512], pmaxT[GB3]
#define PART_OFF 0
#define PART_SZ  (NG*NT2*MGRP*128)       // 2097152
#define YN_OFF   (PART_OFF + PART_SZ)
#define PMY_OFF  (YN_OFF + MDIM*CDIM)
#define PMT_OFF  (PMY_OFF + MDIM)

// K1: fused bilinear-resize + l-conv + H-mult + CASSI diagonal partial sums.
// Block = (m-group g of 4 rows, n-tile of 16). 10 input rows serve FOUR
// output rows (X touched 1.25x; r9 pair version was 1.5x). LDS kept at
// 25.3 KB (r10's 49.6 KB MGRP=4 variant collapsed occupancy — the fix is
// narrower tiles, not fewer blocks). Clamped/garbage values are consumed
// only with zero weights:
//   col -1 / 1024 -> wx0/wx3 = 0 at n = 0/511
//   row -1 / 1024 -> W[0][0]/W[3][3] = 0 at m = 0/511
__global__ __launch_bounds__(256) void k1_fused(const float* __restrict__ X,
                                                const float* __restrict__ H,
                                                float* __restrict__ part) {
    __shared__ float xv[MGRP][SEGF];        // 16.9 KB vertically-resized tiles
    __shared__ float xm[MGRP][TNK][33];     // 8.4 KB H*conv tiles, padded

    const int bid = blockIdx.x;
    const int t   = bid & (NT2-1);
    const int g   = bid >> 5;
    const int n0  = t * TNK;
    const int tid = threadIdx.x;
    const int qa  = 992*t - 32;             // float4-aligned staged-q origin

    // vertical weights W[k][a] for output row m = 4g+k, taps rr = 2k+a
    float W[4][4];
    #pragma unroll
    for (int k = 0; k < 4; ++k) {
        W[k][0]=0.125f; W[k][1]=0.375f; W[k][2]=0.375f; W[k][3]=0.125f;
    }
    if (g == 0)    { const float s=1.0f/0.875f; W[0][0]=0.f; W[0][1]=0.375f*s; W[0][2]=0.375f*s; W[0][3]=0.125f*s; }
    if (g == NG-1) { const float s=1.0f/0.875f; W[3][3]=0.f; W[3][0]=0.125f*s; W[3][1]=0.375f*s; W[3][2]=0.375f*s; }

    const float* rowp[10];
    #pragma unroll
    for (int rr = 0; rr < 10; ++rr)
        rowp[rr] = X + (size_t)min(max(8*g - 1 + rr, 0), INW-1) * RS;

    // ---- phase 1: stream 10 rows, vertical 4-tap for 4 outputs ----
    for (int u = tid; u < SEGF/4; u += 256) {       // 264 float4s
        const int q = min(max(qa + 4*u, 0), RS - 4); // clamp -> zero-weight taps
        float4 acc[4];
        #pragma unroll
        for (int k = 0; k < 4; ++k) acc[k] = make_float4(0.f,0.f,0.f,0.f);
        #pragma unroll
        for (int rr = 0; rr < 10; ++rr) {
            const float4 r = *(const float4*)(rowp[rr] + q);
            #pragma unroll
            for (int k = 0; k < 4; ++k) {
                if (rr >= 2*k && rr <= 2*k + 3) {   // compile-time predicate
                    const float w = W[k][rr - 2*k];
                    acc[k].x = fmaf(w, r.x, acc[k].x);
                    acc[k].y = fmaf(w, r.y, acc[k].y);
                    acc[k].z = fmaf(w, r.z, acc[k].z);
                    acc[k].w = fmaf(w, r.w, acc[k].w);
                }
            }
        }
        #pragma unroll
        for (int k = 0; k < 4; ++k) *(float4*)&xv[k][4*u] = acc[k];
    }
    __syncthreads();

    // ---- phase 2: l-conv + horizontal 4-tap + H multiply -> xm tiles ----
    // xv[mm][i] holds vert(q = qa + i); tap (col = 2n-1+b, l) at
    // i = 2*nl*31 + 31*b + l + 1  (max 1054 < 1056).
    const size_t hbase = ((size_t)(MGRP*g)*MDIM + n0)*LCH;
    for (int idx = tid; idx < MGRP*TNK*LCH; idx += 256) {   // 1984
        const int mm = idx / (TNK*LCH);
        const int r2 = idx - mm*(TNK*LCH);
        const int nl = r2 / 31;
        const int l  = r2 - nl*31;
        const int n  = n0 + nl;
        float wx0=0.125f, wx1=0.375f, wx2=0.375f, wx3=0.125f;
        if (n == 0)      wx0 = 0.f;
        if (n == MDIM-1) wx3 = 0.f;
        if (n == 0 || n == MDIM-1) {
            const float s = 1.0f/0.875f;
            wx0*=s; wx1*=s; wx2*=s; wx3*=s;
        }
        const float wb4[4] = {wx0, wx1, wx2, wx3};
        const float* xvm = xv[mm];
        const int ib = 2*nl*31 + l + 1;
        float acc = 0.f;
        #pragma unroll
        for (int b = 0; b < 4; ++b) {
            const float* q = xvm + ib + 31*b;
            float c = 0.5f*q[0];
            if (l > 0)  c += 0.25f*q[-1];
            if (l < 30) c += 0.25f*q[1];
            acc = fmaf(wb4[b], c, acc);
        }
        xm[mm][nl][l] = acc * H[hbase + (size_t)mm*(MDIM*LCH) + r2];
    }
    __syncthreads();

    // ---- phase 3: diagonal partials: cl = c - n0 in [0,46), 2 halves ----
    #pragma unroll
    for (int base = 0; base < 2*MGRP*DIAG; base += 256) {    // 368 tasks
        const int idx = base + tid;
        if (idx < 2*MGRP*DIAG) {
            const int mm = idx / (2*DIAG);
            const int r3 = idx - mm*(2*DIAG);
            const int h  = r3 >= DIAG;
            const int cl = h ? r3 - DIAG : r3;
            const int ilo = max(0, cl - (TNK-1));
            const int ihi = min(30, cl);
            const int mid = (ilo + ihi + 1) >> 1;
            const int lo  = h ? mid : ilo;
            const int hi  = h ? ihi : mid - 1;
            float s = 0.f;
            for (int i = lo; i <= hi; ++i)
                s += xm[mm][cl - i][i];          // stride-33 -> conflict-free
            part[(((size_t)g*NT2 + t)*MGRP + mm)*128 + h*64 + cl] = s;
        }
    }
}

// K2_lite: yn[m][c] = sum of <=3 tile-partials x 2 halves; per-row max.
__global__ __launch_bounds__(256) void k2_lite(const float* __restrict__ part,
                                               float* __restrict__ yn,
                                               float* __restrict__ pmaxY) {
    const int m = blockIdx.x;
    const int g = m >> 2, mm = m & 3;
    float lmax = -3.4e38f;
    for (int c = threadIdx.x; c < CDIM; c += 256) {
        float s = 0.f;
        const int tlo = max(0, (c - 30) >> 4);      // ceil((c-45)/16)
        const int thi = min(NT2 - 1, c >> 4);
        for (int t = tlo; t <= thi; ++t) {
            const int cl = c - TNK*t;               // in [0,46)
            const float* pp = part + (((size_t)g*NT2 + t)*MGRP + mm)*128;
            s += pp[cl] + pp[64 + cl];
        }
        yn[m*CDIM + c] = s;
        lmax = fmaxf(lmax, s);
    }
    __shared__ float red[256];
    red[threadIdx.x] = lmax; __syncthreads();
    for (int s = 128; s > 0; s >>= 1) {
        if ((int)threadIdx.x < s)
            red[threadIdx.x] = fmaxf(red[threadIdx.x], red[threadIdx.x+s]);
        __syncthreads();
    }
    if (threadIdx.x == 0) pmaxY[m] = red[0];
}

// block-uniform reduction of an L2-resident partial-max array (deterministic:
// every block computes the identical max; order-free).
__device__ __forceinline__ float block_max_of(const float* __restrict__ arr,
                                              int n, float* red) {
    float lm = -3.4e38f;
    for (int i = threadIdx.x; i < n; i += 256)
        lm = fmaxf(lm, arr[i]);
    __syncthreads();
    red[threadIdx.x] = lm; __syncthreads();
    for (int s = 128; s > 0; s >>= 1) {
        if ((int)threadIdx.x < s)
            red[threadIdx.x] = fmaxf(red[threadIdx.x], red[threadIdx.x+s]);
        __syncthreads();
    }
    return red[0];
}

// t(idx) = H[idx] * conv_i(yn/My - y at c=n+i)
__device__ __forceinline__ float t_elem(int idx,
                                        const float* __restrict__ yn,
                                        const float* __restrict__ y,
                                        const float* __restrict__ H,
                                        float inv) {
    const int i    = idx % LCH;
    const int rest = idx / LCH;
    const int n    = rest & (MDIM-1);
    const int m    = rest >> 9;
    const int c    = n + i;
    const float* ynr = yn + (size_t)m*CDIM;
    const float* yr  = y  + (size_t)m*CDIM;
    float v = 0.5f * (ynr[c]*inv - yr[c]);
    if (i > 0)     v += 0.25f*(ynr[c-1]*inv - yr[c-1]);
    if (i < LCH-1) v += 0.25f*(ynr[c+1]*inv - yr[c+1]);
    return H[idx]*v;
}

// K3: self-reduce pmaxY -> invY; block-max of t -> pmaxT[bid]. No t stores.
__global__ __launch_bounds__(256) void k3_max(const float* __restrict__ yn,
                                              const float* __restrict__ y,
                                              const float* __restrict__ H,
                                              const float* __restrict__ pmaxY,
                                              float* __restrict__ pmaxT) {
    __shared__ float red[256];
    const float invY = 1.0f / block_max_of(pmaxY, MDIM, red);
    float lmax = -3.4e38f;
    for (int idx = blockIdx.x*blockDim.x + threadIdx.x; idx < NELEM;
         idx += GB3*256)
        lmax = fmaxf(lmax, t_elem(idx, yn, y, H, invY));
    __syncthreads();
    red[threadIdx.x] = lmax; __syncthreads();
    for (int s = 128; s > 0; s >>= 1) {
        if ((int)threadIdx.x < s)
            red[threadIdx.x] = fmaxf(red[threadIdx.x], red[threadIdx.x+s]);
        __syncthreads();
    }
    if (threadIdx.x == 0) pmaxT[blockIdx.x] = red[0];
}

// K4: self-reduce pmaxY, pmaxT -> invY, invT; recompute t, write scaled out.
__global__ __launch_bounds__(256) void k4_out(const float* __restrict__ yn,
                                              const float* __restrict__ y,
                                              const float* __restrict__ H,
                                              const float* __restrict__ pmaxY,
                                              const float* __restrict__ pmaxT,
                                              float* __restrict__ out) {
    __shared__ float red[256];
    const float invY = 1.0f / block_max_of(pmaxY, MDIM, red);
    __syncthreads();
    const float invT = 1.0f / block_max_of(pmaxT, GB3, red);
    for (int idx = blockIdx.x*blockDim.x + threadIdx.x; idx < NELEM;
         idx += GB3*256)
        out[idx] = t_elem(idx, yn, y, H, invY) * invT;
}

extern "C" void kernel_launch(void* const* d_in, const int* in_sizes, int n_in,
                              void* d_out, int out_size, void* d_ws, size_t ws_size,
                              hipStream_t stream) {
    const float* X = (const float*)d_in[0];
    const float* y = (const float*)d_in[1];
    const float* H = (const float*)d_in[2];
    float* out = (float*)d_out;
    float* ws  = (float*)d_ws;

    float* part  = ws + PART_OFF;
    float* yn    = ws + YN_OFF;
    float* pmaxY = ws + PMY_OFF;
    float* pmaxT = ws + PMT_OFF;

    k1_fused<<<NG*NT2, 256, 0, stream>>>(X, H, part);       // 4096 blocks
    k2_lite<<<MDIM, 256, 0, stream>>>(part, yn, pmaxY);     // 512 blocks
    k3_max<<<GB3, 256, 0, stream>>>(yn, y, H, pmaxY, pmaxT);
    k4_out<<<GB3, 256, 0, stream>>>(yn, y, H, pmaxY, pmaxT, out);
}